// Round 1
// baseline (1925.753 us; speedup 1.0000x reference)
//
#include <hip/hip_runtime.h>

#define NH 256
#define NS 39
#define NA 4
#define ND 43
#define NT 2048
#define NROWS 32

__global__ void zero_out_kernel(float* __restrict__ out, int n) {
  int i = blockIdx.x * blockDim.x + threadIdx.x;
  if (i < n) out[i] = 0.f;
}

__launch_bounds__(256, 4)
__global__ void srm_kernel(const float* __restrict__ obs,
                           const float* __restrict__ act,
                           const float* __restrict__ W1, const float* __restrict__ b1,
                           const float* __restrict__ g1, const float* __restrict__ be1,
                           const float* __restrict__ W2, const float* __restrict__ b2,
                           const float* __restrict__ g2, const float* __restrict__ be2,
                           const float* __restrict__ W3, const float* __restrict__ b3,
                           float* __restrict__ out) {
  __shared__ float xs[NROWS][44];        // 43 padded to 44 (float4-aligned rows)
  __shared__ float h1s[NROWS][NH];       // 32 KB
  __shared__ float redS[NROWS][4];
  __shared__ float redQ[NROWS][4];
  __shared__ float mean_s[NROWS];
  __shared__ float rstd_s[NROWS];
  __shared__ float bsum[4];

  const int tile = blockIdx.x;
  const long row0 = (long)tile * NROWS;       // global row base
  const int bidx = (int)(row0 / NT);          // batch index (all rows in tile share it)
  const int h = threadIdx.x;                  // output column 0..255
  const int wave = h >> 6;
  const int lane = h & 63;

  // ---- stage x tile into LDS (obs tile is contiguous: row0*39 .. +32*39) ----
  for (int idx = h; idx < NROWS * NS; idx += 256) {
    int r = idx / NS, c = idx - r * NS;
    xs[r][c] = obs[row0 * NS + idx];
  }
  for (int idx = h; idx < NROWS * NA; idx += 256) {
    int r = idx >> 2, c = idx & 3;
    xs[r][NS + c] = act[row0 * NA + idx];
  }
  if (h < NROWS) xs[h][ND] = 0.f;   // zero the pad column (d=43)
  __syncthreads();

  // ---- layer 1: acc[r] = dot(x[r], W1[:,h]) ----
  float acc[NROWS];
  #pragma unroll
  for (int r = 0; r < NROWS; ++r) acc[r] = 0.f;

  for (int d0 = 0; d0 < 44; d0 += 4) {
    float w0 = W1[(d0 + 0) * NH + h];
    float w1 = W1[(d0 + 1) * NH + h];
    float w2 = W1[(d0 + 2) * NH + h];
    float w3 = (d0 + 3 < ND) ? W1[(d0 + 3) * NH + h] : 0.f;  // d=43 is pad
    #pragma unroll
    for (int r = 0; r < NROWS; ++r) {
      const float4 v = *reinterpret_cast<const float4*>(&xs[r][d0]);
      acc[r] = fmaf(v.x, w0, acc[r]);
      acc[r] = fmaf(v.y, w1, acc[r]);
      acc[r] = fmaf(v.z, w2, acc[r]);
      acc[r] = fmaf(v.w, w3, acc[r]);
    }
  }
  {
    float bb = b1[h];
    #pragma unroll
    for (int r = 0; r < NROWS; ++r) acc[r] += bb;
  }

  // ---- LN1 stats: block-wide sum & sumsq per row ----
  #pragma unroll
  for (int r = 0; r < NROWS; ++r) {
    float s = acc[r];
    float q = s * s;
    #pragma unroll
    for (int off = 32; off > 0; off >>= 1) {
      s += __shfl_xor(s, off);
      q += __shfl_xor(q, off);
    }
    if (lane == 0) { redS[r][wave] = s; redQ[r][wave] = q; }
  }
  __syncthreads();
  if (h < NROWS) {
    int r = h;
    float s = redS[r][0] + redS[r][1] + redS[r][2] + redS[r][3];
    float q = redQ[r][0] + redQ[r][1] + redQ[r][2] + redQ[r][3];
    float mean = s * (1.f / NH);
    float var  = q * (1.f / NH) - mean * mean;
    mean_s[r] = mean;
    rstd_s[r] = rsqrtf(var + 1e-5f);
  }
  __syncthreads();
  {
    float gg = g1[h], ee = be1[h];
    #pragma unroll
    for (int r = 0; r < NROWS; ++r) {
      float v = (acc[r] - mean_s[r]) * rstd_s[r] * gg + ee;
      h1s[r][h] = fmaxf(v, 0.f);
    }
  }
  __syncthreads();

  // ---- layer 2: acc[r] = dot(h1[r], W2[:,h]) ----
  #pragma unroll
  for (int r = 0; r < NROWS; ++r) acc[r] = 0.f;

  for (int k0 = 0; k0 < NH; k0 += 4) {
    float w0 = W2[(k0 + 0) * NH + h];
    float w1 = W2[(k0 + 1) * NH + h];
    float w2 = W2[(k0 + 2) * NH + h];
    float w3 = W2[(k0 + 3) * NH + h];
    #pragma unroll
    for (int r = 0; r < NROWS; ++r) {
      const float4 v = *reinterpret_cast<const float4*>(&h1s[r][k0]);
      acc[r] = fmaf(v.x, w0, acc[r]);
      acc[r] = fmaf(v.y, w1, acc[r]);
      acc[r] = fmaf(v.z, w2, acc[r]);
      acc[r] = fmaf(v.w, w3, acc[r]);
    }
  }
  {
    float bb = b2[h];
    #pragma unroll
    for (int r = 0; r < NROWS; ++r) acc[r] += bb;
  }

  // ---- LN2 stats ----
  #pragma unroll
  for (int r = 0; r < NROWS; ++r) {
    float s = acc[r];
    float q = s * s;
    #pragma unroll
    for (int off = 32; off > 0; off >>= 1) {
      s += __shfl_xor(s, off);
      q += __shfl_xor(q, off);
    }
    if (lane == 0) { redS[r][wave] = s; redQ[r][wave] = q; }
  }
  __syncthreads();
  if (h < NROWS) {
    int r = h;
    float s = redS[r][0] + redS[r][1] + redS[r][2] + redS[r][3];
    float q = redQ[r][0] + redQ[r][1] + redQ[r][2] + redQ[r][3];
    float mean = s * (1.f / NH);
    float var  = q * (1.f / NH) - mean * mean;
    mean_s[r] = mean;
    rstd_s[r] = rsqrtf(var + 1e-5f);
  }
  __syncthreads();

  // ---- LN2 apply + ReLU + W3 dot + segment partial sum ----
  float p = 0.f;
  {
    float gg = g2[h], ee = be2[h];
    #pragma unroll
    for (int r = 0; r < NROWS; ++r) {
      float v = (acc[r] - mean_s[r]) * rstd_s[r] * gg + ee;
      p += fmaxf(v, 0.f);
    }
  }
  p *= W3[h];

  #pragma unroll
  for (int off = 32; off > 0; off >>= 1) p += __shfl_xor(p, off);
  if (lane == 0) bsum[wave] = p;
  __syncthreads();
  if (h == 0) {
    float tot = bsum[0] + bsum[1] + bsum[2] + bsum[3] + (float)NROWS * b3[0];
    atomicAdd(&out[bidx], tot);
  }
}

extern "C" void kernel_launch(void* const* d_in, const int* in_sizes, int n_in,
                              void* d_out, int out_size, void* d_ws, size_t ws_size,
                              hipStream_t stream) {
  const float* obs = (const float*)d_in[0];
  const float* act = (const float*)d_in[1];
  const float* W1  = (const float*)d_in[2];
  const float* b1  = (const float*)d_in[3];
  const float* g1  = (const float*)d_in[4];
  const float* be1 = (const float*)d_in[5];
  const float* W2  = (const float*)d_in[6];
  const float* b2  = (const float*)d_in[7];
  const float* g2  = (const float*)d_in[8];
  const float* be2 = (const float*)d_in[9];
  const float* W3  = (const float*)d_in[10];
  const float* b3  = (const float*)d_in[11];
  float* out = (float*)d_out;

  zero_out_kernel<<<1, 256, 0, stream>>>(out, out_size);

  const int n_rows = 256 * 2048;           // B * T
  const int n_tiles = n_rows / NROWS;      // 16384
  srm_kernel<<<n_tiles, 256, 0, stream>>>(obs, act, W1, b1, g1, be1,
                                          W2, b2, g2, be2, W3, b3, out);
}

// Round 2
// 334.059 us; speedup vs baseline: 5.7647x; 5.7647x over previous
//
#include <hip/hip_runtime.h>
#include <hip/hip_bf16.h>

typedef __attribute__((ext_vector_type(8))) short short8;
typedef __attribute__((ext_vector_type(4))) float f32x4;

#define NT 2048
#define ROWS_PER_BLOCK 128
#define NROWS_WAVE 32

__device__ __forceinline__ short f2bf(float x) {
  __hip_bfloat16 h = __float2bfloat16(x);
  return __builtin_bit_cast(short, h);
}

__global__ void zero_out_kernel(float* __restrict__ out, int n) {
  int i = blockIdx.x * blockDim.x + threadIdx.x;
  if (i < n) out[i] = 0.f;
}

// Pack W1 (43x256, K-padded to 64) and W2 (256x256) from f32 row-major [k][n]
// into bf16 MFMA B-fragment order: frag f = (s*16+t)*64+lane holds 8 bf16,
// elem i = W[k = s*32+(lane>>4)*8+i][n = t*16+(lane&15)].
__global__ void repack_kernel(const float* __restrict__ W1, const float* __restrict__ W2,
                              short* __restrict__ Wp) {
  int id = blockIdx.x * 256 + threadIdx.x;   // 0..10239
  const float* W; int kmax; long dstbase; int f;
  if (id < 2048) { f = id;        W = W1; kmax = 43;  dstbase = (long)f * 8; }
  else           { f = id - 2048; W = W2; kmax = 256; dstbase = 2048L * 8 + (long)f * 8; }
  int lane = f & 63; int ts = f >> 6; int t = ts & 15; int s = ts >> 4;
  int k0 = s * 32 + (lane >> 4) * 8;
  int n  = t * 16 + (lane & 15);
  short8 v;
  #pragma unroll
  for (int i = 0; i < 8; ++i) {
    int k = k0 + i;
    float x = (k < kmax) ? W[(long)k * 256 + n] : 0.f;
    v[i] = f2bf(x);
  }
  *(short8*)(Wp + dstbase) = v;
}

__launch_bounds__(256, 2)
__global__ void srm_mfma(const float* __restrict__ obs, const float* __restrict__ act,
                         const float* __restrict__ b1, const float* __restrict__ g1,
                         const float* __restrict__ be1,
                         const float* __restrict__ b2, const float* __restrict__ g2,
                         const float* __restrict__ be2,
                         const float* __restrict__ W3, const float* __restrict__ b3,
                         const short* __restrict__ Wp, float* __restrict__ out) {
  // param arrays transposed to [lr][t] so a lane reads 2-4 t's per ds_read_b128
  __shared__ float  bl1[16][20], bl2[16][20], w3l[16][20];   // pad 20: 2-way banks only
  __shared__ float2 gbl1[16][18], gbl2[16][18];              // (gamma, beta) pairs
  __shared__ short  H1buf[4][NROWS_WAVE * 256];              // 16 KB per wave, XOR-swizzled

  const int tid = threadIdx.x;
  const int wave = tid >> 6, lane = tid & 63;
  const int lr = lane & 15, lg = lane >> 4;

  { // one-time param staging
    int c = tid;
    bl1[c & 15][c >> 4] = b1[c];
    bl2[c & 15][c >> 4] = b2[c];
    w3l[c & 15][c >> 4] = W3[c];
    gbl1[c & 15][c >> 4] = make_float2(g1[c], be1[c]);
    gbl2[c & 15][c >> 4] = make_float2(g2[c], be2[c]);
  }
  __syncthreads();

  const int row0 = blockIdx.x * ROWS_PER_BLOCK + wave * NROWS_WAVE;
  const int bidx = row0 / NT;
  const float b3v = b3[0];

  short* H1 = &H1buf[wave][0];
  const short8* W1v = (const short8*)Wp;               // 2048 frags
  const short8* W2v = (const short8*)(Wp + 2048L * 8); // 8192 frags

  f32x4 acc[2][16];
  #pragma unroll
  for (int rt = 0; rt < 2; ++rt)
    #pragma unroll
    for (int t = 0; t < 16; ++t) acc[rt][t] = (f32x4)0.f;

  // ---------------- layer 1: X(32x64 padded) @ W1 ----------------
  #pragma unroll
  for (int s = 0; s < 2; ++s) {
    short8 a[2];
    #pragma unroll
    for (int rt = 0; rt < 2; ++rt) {
      const int row = row0 + rt * 16 + lr;     // A-frag: row = lane&15
      #pragma unroll
      for (int i = 0; i < 8; ++i) {
        int k = s * 32 + lg * 8 + i;           // k = (lane>>4)*8+i, contiguous
        float x = 0.f;
        if (k < 39)      x = obs[(long)row * 39 + k];
        else if (k < 43) x = act[(long)row * 4 + (k - 39)];
        a[rt][i] = f2bf(x);
      }
    }
    #pragma unroll
    for (int t = 0; t < 16; ++t) {
      short8 bf = W1v[(s * 16 + t) * 64 + lane];
      acc[0][t] = __builtin_amdgcn_mfma_f32_16x16x32_bf16(a[0], bf, acc[0][t], 0, 0, 0);
      acc[1][t] = __builtin_amdgcn_mfma_f32_16x16x32_bf16(a[1], bf, acc[1][t], 0, 0, 0);
    }
  }

  f32x4 mean_[2], rstd_[2];

  // ---- LN1: bias + stats (C layout: col = t*16+lr, row = rt*16+lg*4+qd) ----
  {
    f32x4 s_[2] = {(f32x4)0.f, (f32x4)0.f}, q_[2] = {(f32x4)0.f, (f32x4)0.f};
    #pragma unroll
    for (int t0 = 0; t0 < 4; ++t0) {
      f32x4 bv = *(const f32x4*)&bl1[lr][t0 * 4];
      #pragma unroll
      for (int j = 0; j < 4; ++j) {
        int t = t0 * 4 + j;
        #pragma unroll
        for (int rt = 0; rt < 2; ++rt) {
          f32x4 v = acc[rt][t] + bv[j];
          acc[rt][t] = v;
          s_[rt] += v; q_[rt] += v * v;
        }
      }
    }
    #pragma unroll
    for (int rt = 0; rt < 2; ++rt)
      #pragma unroll
      for (int qd = 0; qd < 4; ++qd) {
        float s = s_[rt][qd], q = q_[rt][qd];
        #pragma unroll
        for (int off = 1; off < 16; off <<= 1) { s += __shfl_xor(s, off); q += __shfl_xor(q, off); }
        float m = s * (1.f / 256.f);
        float var = q * (1.f / 256.f) - m * m;
        mean_[rt][qd] = m;
        rstd_[rt][qd] = rsqrtf(var + 1e-5f);
      }
  }

  // ---- LN1 apply + ReLU + bf16 -> H1 LDS (swizzled row-major [32][256]) ----
  #pragma unroll
  for (int t2 = 0; t2 < 8; ++t2) {
    f32x4 gg = *(const f32x4*)&gbl1[lr][t2 * 2];   // g(t),be(t),g(t+1),be(t+1)
    #pragma unroll
    for (int hh = 0; hh < 2; ++hh) {
      int t = t2 * 2 + hh;
      float g_ = gg[hh * 2], be_ = gg[hh * 2 + 1];
      int colb = t * 16 + lr;
      #pragma unroll
      for (int rt = 0; rt < 2; ++rt) {
        f32x4 v = (acc[rt][t] - mean_[rt]) * rstd_[rt] * g_ + be_;
        #pragma unroll
        for (int qd = 0; qd < 4; ++qd) {
          float vv = fmaxf(v[qd], 0.f);
          int row = rt * 16 + lg * 4 + qd;
          H1[row * 256 + (colb ^ ((row & 7) << 3))] = f2bf(vv);
        }
      }
    }
  }

  // ---------------- layer 2: H1(32x256) @ W2 ----------------
  #pragma unroll
  for (int rt = 0; rt < 2; ++rt)
    #pragma unroll
    for (int t = 0; t < 16; ++t) acc[rt][t] = (f32x4)0.f;

  #pragma unroll 2
  for (int s = 0; s < 8; ++s) {
    short8 a[2];
    #pragma unroll
    for (int rt = 0; rt < 2; ++rt) {
      int arow = rt * 16 + lr;
      a[rt] = *(const short8*)&H1[arow * 256 + ((s * 32 + lg * 8) ^ ((arow & 7) << 3))];
    }
    #pragma unroll
    for (int t = 0; t < 16; ++t) {
      short8 bf = W2v[(s * 16 + t) * 64 + lane];
      acc[0][t] = __builtin_amdgcn_mfma_f32_16x16x32_bf16(a[0], bf, acc[0][t], 0, 0, 0);
      acc[1][t] = __builtin_amdgcn_mfma_f32_16x16x32_bf16(a[1], bf, acc[1][t], 0, 0, 0);
    }
  }

  // ---- LN2: bias + stats ----
  {
    f32x4 s_[2] = {(f32x4)0.f, (f32x4)0.f}, q_[2] = {(f32x4)0.f, (f32x4)0.f};
    #pragma unroll
    for (int t0 = 0; t0 < 4; ++t0) {
      f32x4 bv = *(const f32x4*)&bl2[lr][t0 * 4];
      #pragma unroll
      for (int j = 0; j < 4; ++j) {
        int t = t0 * 4 + j;
        #pragma unroll
        for (int rt = 0; rt < 2; ++rt) {
          f32x4 v = acc[rt][t] + bv[j];
          acc[rt][t] = v;
          s_[rt] += v; q_[rt] += v * v;
        }
      }
    }
    #pragma unroll
    for (int rt = 0; rt < 2; ++rt)
      #pragma unroll
      for (int qd = 0; qd < 4; ++qd) {
        float s = s_[rt][qd], q = q_[rt][qd];
        #pragma unroll
        for (int off = 1; off < 16; off <<= 1) { s += __shfl_xor(s, off); q += __shfl_xor(q, off); }
        float m = s * (1.f / 256.f);
        float var = q * (1.f / 256.f) - m * m;
        mean_[rt][qd] = m;
        rstd_[rt][qd] = rsqrtf(var + 1e-5f);
      }
  }

  // ---- LN2 apply + ReLU + dot W3 + segment sum ----
  float p = 0.f;
  #pragma unroll
  for (int t0 = 0; t0 < 4; ++t0) {
    f32x4 wv = *(const f32x4*)&w3l[lr][t0 * 4];
    #pragma unroll
    for (int h2 = 0; h2 < 2; ++h2) {
      f32x4 gg = *(const f32x4*)&gbl2[lr][t0 * 4 + h2 * 2];
      #pragma unroll
      for (int hh = 0; hh < 2; ++hh) {
        int t = t0 * 4 + h2 * 2 + hh;
        float g_ = gg[hh * 2], be_ = gg[hh * 2 + 1];
        float w_ = wv[h2 * 2 + hh];
        #pragma unroll
        for (int rt = 0; rt < 2; ++rt) {
          f32x4 v = (acc[rt][t] - mean_[rt]) * rstd_[rt] * g_ + be_;
          #pragma unroll
          for (int qd = 0; qd < 4; ++qd) p += fmaxf(v[qd], 0.f) * w_;
        }
      }
    }
  }
  #pragma unroll
  for (int off = 1; off < 64; off <<= 1) p += __shfl_xor(p, off);
  if (lane == 0) atomicAdd(&out[bidx], p + 32.f * b3v);
}

extern "C" void kernel_launch(void* const* d_in, const int* in_sizes, int n_in,
                              void* d_out, int out_size, void* d_ws, size_t ws_size,
                              hipStream_t stream) {
  const float* obs = (const float*)d_in[0];
  const float* act = (const float*)d_in[1];
  const float* W1  = (const float*)d_in[2];
  const float* b1  = (const float*)d_in[3];
  const float* g1  = (const float*)d_in[4];
  const float* be1 = (const float*)d_in[5];
  const float* W2  = (const float*)d_in[6];
  const float* b2  = (const float*)d_in[7];
  const float* g2  = (const float*)d_in[8];
  const float* be2 = (const float*)d_in[9];
  const float* W3  = (const float*)d_in[10];
  const float* b3  = (const float*)d_in[11];
  float* out = (float*)d_out;

  zero_out_kernel<<<1, 256, 0, stream>>>(out, out_size);

  short* Wp = (short*)d_ws;   // needs (2048+8192)*8 shorts = 160 KB
  repack_kernel<<<40, 256, 0, stream>>>(W1, W2, Wp);

  const int n_rows = 256 * 2048;
  srm_mfma<<<n_rows / ROWS_PER_BLOCK, 256, 0, stream>>>(
      obs, act, b1, g1, be1, b2, g2, be2, W3, b3, Wp, out);
}